// Round 1
// baseline (742.829 us; speedup 1.0000x reference)
//
#include <hip/hip_runtime.h>

typedef __attribute__((ext_vector_type(8))) short short8;
typedef __attribute__((ext_vector_type(4))) float f32x4;
typedef __attribute__((ext_vector_type(4))) unsigned short u16x4;
typedef __attribute__((ext_vector_type(8))) unsigned short u16x8;

#define H 112
#define W 112
#define CIN 128
#define COUT 256
#define NPIX (H * W)          // 12544
#define NIMG 32
#define MTOT (NIMG * NPIX)    // 401408

// round-to-nearest-even f32 -> bf16 bits
__device__ __forceinline__ unsigned short f2bf(float f) {
    unsigned int u = __builtin_bit_cast(unsigned int, f);
    u += 0x7FFFu + ((u >> 16) & 1u);
    return (unsigned short)(u >> 16);
}

// Binarize weights into ws as bf16 {+1,-1}, layout [tap][kc4][cout][cin5]
// index = ((tap*4 + kc4)*256 + cout)*32 + cin5   (tap<9, kc4<4, cout<256, cin5<32)
__global__ void binw_kernel(const float* __restrict__ kw, unsigned short* __restrict__ bw) {
    int tid = blockIdx.x * 256 + threadIdx.x;
    int cin5 = tid & 31;
    int cout = (tid >> 5) & 255;
    int kc4  = (tid >> 13) & 3;
    int tap  = tid >> 15;
    int cin  = kc4 * 32 + cin5;
    float w = kw[(tap * 128 + cin) * 256 + cout];
    bw[tid] = (w >= 0.0f) ? (unsigned short)0x3F80u : (unsigned short)0xBF80u;
}

// Implicit-GEMM binary conv: M=NHW pixels, N=cout, K=9 taps x 128 cin.
// 128x128 tile, 4 waves (2x2), each wave 64x64 via 4x4 frags of 16x16x32 bf16 MFMA.
__global__ __launch_bounds__(256, 2)
void conv_kernel(const float* __restrict__ x, const unsigned short* __restrict__ bw,
                 float* __restrict__ out) {
    __shared__ unsigned short As[128][40];  // [pixel][cin32], +8 pad
    __shared__ unsigned short Bs[128][40];  // [cout][cin32],  +8 pad

    const int tid = threadIdx.x;
    const int bm = blockIdx.x;
    const int bn = blockIdx.y;
    const int lane = tid & 63;
    const int wv = tid >> 6;
    const int wr = wv >> 1, wc = wv & 1;

    // A-staging coords: thread covers 4 rows (rseg + 32*i), 4 cin each
    const int c4 = (tid & 7) * 4;
    const int rseg = tid >> 3;

    int ohs[4], ows[4], bases[4];
#pragma unroll
    for (int i = 0; i < 4; ++i) {
        int p = bm * 128 + rseg + i * 32;
        int n = p / NPIX;
        int rem = p - n * NPIX;
        int oh = rem / W;
        int ow = rem - oh * W;
        ohs[i] = oh; ows[i] = ow;
        bases[i] = ((n * H + oh) * W + ow) * CIN;
    }

    f32x4 acc[4][4];
#pragma unroll
    for (int m = 0; m < 4; ++m)
#pragma unroll
        for (int n = 0; n < 4; ++n)
            acc[m][n] = (f32x4){0.f, 0.f, 0.f, 0.f};

    const int arow = wr * 64 + (lane & 15);
    const int brow = wc * 64 + (lane & 15);
    const int koff = (lane >> 4) * 8;

    for (int tap = 0; tap < 9; ++tap) {
        const int dh = tap / 3 - 1;
        const int dw = tap % 3 - 1;
        const int shift = (dh * W + dw) * CIN;
#pragma unroll
        for (int kc = 0; kc < 4; ++kc) {
            __syncthreads();
            // --- stage A: 128 pixels x 32 cin, f32 -> bf16, halo zero-masked ---
#pragma unroll
            for (int i = 0; i < 4; ++i) {
                int ih = ohs[i] + dh, iw = ows[i] + dw;
                bool valid = ((unsigned)ih < (unsigned)H) & ((unsigned)iw < (unsigned)W);
                f32x4 v = {0.f, 0.f, 0.f, 0.f};
                if (valid) v = *(const f32x4*)(x + bases[i] + shift + kc * 32 + c4);
                u16x4 s = { f2bf(v.x), f2bf(v.y), f2bf(v.z), f2bf(v.w) };
                *(u16x4*)&As[rseg + i * 32][c4] = s;
            }
            // --- stage B: contiguous 8KB block of pre-binarized bf16 weights ---
            const unsigned short* bp = bw + tap * 32768 + kc * 8192 + bn * 4096;
#pragma unroll
            for (int j = 0; j < 2; ++j) {
                int idx = tid + j * 256;
                int cr = idx >> 2;
                int c8 = (idx & 3) * 8;
                *(u16x8*)&Bs[cr][c8] = *(const u16x8*)(bp + cr * 32 + c8);
            }
            __syncthreads();

            short8 af[4], bf[4];
#pragma unroll
            for (int m = 0; m < 4; ++m)
                af[m] = *(const short8*)&As[arow + m * 16][koff];
#pragma unroll
            for (int n = 0; n < 4; ++n)
                bf[n] = *(const short8*)&Bs[brow + n * 16][koff];
#pragma unroll
            for (int m = 0; m < 4; ++m)
#pragma unroll
                for (int n = 0; n < 4; ++n)
                    acc[m][n] = __builtin_amdgcn_mfma_f32_16x16x32_bf16(af[m], bf[n], acc[m][n], 0, 0, 0);
        }
    }

    // epilogue: C/D layout col=lane&15, row=(lane>>4)*4+reg
    const long row0 = (long)bm * 128 + wr * 64 + ((lane >> 4) * 4);
    const int col = bn * 128 + wc * 64 + (lane & 15);
#pragma unroll
    for (int m = 0; m < 4; ++m)
#pragma unroll
        for (int n = 0; n < 4; ++n)
#pragma unroll
            for (int j = 0; j < 4; ++j)
                out[(row0 + m * 16 + j) * COUT + col + n * 16] = acc[m][n][j];
}

extern "C" void kernel_launch(void* const* d_in, const int* in_sizes, int n_in,
                              void* d_out, int out_size, void* d_ws, size_t ws_size,
                              hipStream_t stream) {
    const float* x  = (const float*)d_in[0];
    const float* kw = (const float*)d_in[1];
    float* out = (float*)d_out;
    unsigned short* bw = (unsigned short*)d_ws;  // 9*4*256*32*2 = 589,824 bytes

    binw_kernel<<<(9 * 256 * 128) / 256, 256, 0, stream>>>(kw, bw);

    dim3 grid(MTOT / 128, COUT / 128);
    conv_kernel<<<grid, 256, 0, stream>>>(x, bw, out);
}

// Round 2
// 363.611 us; speedup vs baseline: 2.0429x; 2.0429x over previous
//
#include <hip/hip_runtime.h>

typedef __attribute__((ext_vector_type(8))) short short8;
typedef __attribute__((ext_vector_type(4))) float f32x4;
typedef __attribute__((ext_vector_type(4))) unsigned short u16x4;
typedef __attribute__((ext_vector_type(8))) unsigned short u16x8;

#define H 112
#define W 112
#define HP 114
#define WP 114
#define CIN 128
#define COUT 256
#define NPIX (H * W)          // 12544
#define NIMG 32
#define MTOT (NIMG * NPIX)    // 401408
#define PADELEMS ((long)NIMG * HP * WP * CIN)  // 53,231,616

// round-to-nearest-even f32 -> bf16 bits
__device__ __forceinline__ unsigned short f2bf(float f) {
    unsigned int u = __builtin_bit_cast(unsigned int, f);
    u += 0x7FFFu + ((u >> 16) & 1u);
    return (unsigned short)(u >> 16);
}

__device__ __forceinline__ void gl2lds16(const void* g, void* l) {
    __builtin_amdgcn_global_load_lds(
        (const __attribute__((address_space(1))) unsigned int*)g,
        (__attribute__((address_space(3))) unsigned int*)l,
        16, 0, 0);
}

// Binarize weights into ws as bf16 {+1,-1}, layout [tap][kc4][cout][cin5]
__global__ void binw_kernel(const float* __restrict__ kw, unsigned short* __restrict__ bw) {
    int tid = blockIdx.x * 256 + threadIdx.x;
    int cin5 = tid & 31;
    int cout = (tid >> 5) & 255;
    int kc4  = (tid >> 13) & 3;
    int tap  = tid >> 15;
    int cin  = kc4 * 32 + cin5;
    float w = kw[(tap * 128 + cin) * 256 + cout];
    bw[tid] = (w >= 0.0f) ? (unsigned short)0x3F80u : (unsigned short)0xBF80u;
}

// Convert x (f32 NHWC) into zero-padded bf16 [N][114][114][128]
__global__ void pad_kernel(const float* __restrict__ x, unsigned short* __restrict__ xp) {
    long tid = (long)blockIdx.x * 256 + threadIdx.x;   // one thread = 8 elems
    if (tid >= PADELEMS / 8) return;
    int c8 = (int)(tid & 15);
    long rem = tid >> 4;
    int wp = (int)(rem % WP); rem /= WP;
    int hp = (int)(rem % HP);
    int n  = (int)(rem / HP);
    u16x8 v = {0, 0, 0, 0, 0, 0, 0, 0};
    if (hp >= 1 && hp <= H && wp >= 1 && wp <= W) {
        const float* s = x + (((long)(n * H + hp - 1) * W + (wp - 1)) * CIN + c8 * 8);
        f32x4 a = *(const f32x4*)s;
        f32x4 b = *(const f32x4*)(s + 4);
        v = (u16x8){ f2bf(a.x), f2bf(a.y), f2bf(a.z), f2bf(a.w),
                     f2bf(b.x), f2bf(b.y), f2bf(b.z), f2bf(b.w) };
    }
    *(u16x8*)(xp + tid * 8) = v;
}

// m97-structure implicit GEMM: 128x128 tile, BK=32, global_load_lds staging.
__global__ __launch_bounds__(256, 2)
void conv2_kernel(const unsigned short* __restrict__ xp, const unsigned short* __restrict__ bw,
                  float* __restrict__ out) {
    __shared__ unsigned short As[128 * 32];  // [pixel][cin32] linear (gload_lds dest)
    __shared__ unsigned short Bs[128 * 32];  // [cout][cin32] linear

    const int tid = threadIdx.x;
    const int bm = blockIdx.x;
    const int bn = blockIdx.y;
    const int lane = tid & 63;
    const int wv = tid >> 6;
    const int wr = wv >> 1, wc = wv & 1;

    // A slot s = tid + j*256 covers LDS bytes [s*16, s*16+16) = pixel s>>2, cin8 (s&3)*8
    long arowbase[2];
#pragma unroll
    for (int j = 0; j < 2; ++j) {
        int s = tid + j * 256;
        int p = bm * 128 + (s >> 2);
        int n = p / NPIX;
        int rem = p - n * NPIX;
        int oh = rem / W, ow = rem - oh * W;
        arowbase[j] = (long)((n * HP + oh + 1) * WP + (ow + 1)) * CIN + (s & 3) * 8;
    }

    f32x4 acc[4][4];
#pragma unroll
    for (int m = 0; m < 4; ++m)
#pragma unroll
        for (int n = 0; n < 4; ++n)
            acc[m][n] = (f32x4){0.f, 0.f, 0.f, 0.f};

    const int arow = wr * 64 + (lane & 15);
    const int brow = wc * 64 + (lane & 15);
    const int koff = (lane >> 4) * 8;

    for (int t = 0; t < 36; ++t) {
        const int tap = t >> 2, kc = t & 3;
        const int dh = tap / 3 - 1, dw = tap % 3 - 1;
        const long shift = (long)(dh * WP + dw) * CIN + kc * 32;

        // stage A: 2 x 16B per thread, per-lane global addr, linear LDS dest
#pragma unroll
        for (int j = 0; j < 2; ++j)
            gl2lds16(xp + arowbase[j] + shift, &As[(j * 256 + wv * 64) * 8]);
        // stage B: contiguous 8KB block of pre-binarized weights
#pragma unroll
        for (int j = 0; j < 2; ++j)
            gl2lds16(bw + (tap * 4 + kc) * 8192 + bn * 4096 + (tid + j * 256) * 8,
                     &Bs[(j * 256 + wv * 64) * 8]);

        __syncthreads();  // drains vmcnt -> staged data visible

        short8 af[4], bfr[4];
#pragma unroll
        for (int m = 0; m < 4; ++m)
            af[m] = *(const short8*)&As[(arow + m * 16) * 32 + koff];
#pragma unroll
        for (int n = 0; n < 4; ++n)
            bfr[n] = *(const short8*)&Bs[(brow + n * 16) * 32 + koff];
#pragma unroll
        for (int m = 0; m < 4; ++m)
#pragma unroll
            for (int n = 0; n < 4; ++n)
                acc[m][n] = __builtin_amdgcn_mfma_f32_16x16x32_bf16(af[m], bfr[n], acc[m][n], 0, 0, 0);

        __syncthreads();  // protect LDS before next-step overwrite
    }

    const long row0 = (long)bm * 128 + wr * 64 + ((lane >> 4) * 4);
    const int col = bn * 128 + wc * 64 + (lane & 15);
#pragma unroll
    for (int m = 0; m < 4; ++m)
#pragma unroll
        for (int n = 0; n < 4; ++n)
#pragma unroll
            for (int j = 0; j < 4; ++j)
                out[(row0 + m * 16 + j) * COUT + col + n * 16] = acc[m][n][j];
}

// ---------------- fallback (round-1) path: no padded buffer needed ----------------
__global__ __launch_bounds__(256, 2)
void conv_fallback_kernel(const float* __restrict__ x, const unsigned short* __restrict__ bw,
                          float* __restrict__ out) {
    __shared__ unsigned short As[128][40];
    __shared__ unsigned short Bs[128][40];
    const int tid = threadIdx.x;
    const int bm = blockIdx.x, bn = blockIdx.y;
    const int lane = tid & 63;
    const int wv = tid >> 6;
    const int wr = wv >> 1, wc = wv & 1;
    const int c4 = (tid & 7) * 4;
    const int rseg = tid >> 3;
    int ohs[4], ows[4], bases[4];
#pragma unroll
    for (int i = 0; i < 4; ++i) {
        int p = bm * 128 + rseg + i * 32;
        int n = p / NPIX;
        int rem = p - n * NPIX;
        int oh = rem / W, ow = rem - oh * W;
        ohs[i] = oh; ows[i] = ow;
        bases[i] = ((n * H + oh) * W + ow) * CIN;
    }
    f32x4 acc[4][4];
#pragma unroll
    for (int m = 0; m < 4; ++m)
#pragma unroll
        for (int n = 0; n < 4; ++n)
            acc[m][n] = (f32x4){0.f, 0.f, 0.f, 0.f};
    const int arow = wr * 64 + (lane & 15);
    const int brow = wc * 64 + (lane & 15);
    const int koff = (lane >> 4) * 8;
    for (int tap = 0; tap < 9; ++tap) {
        const int dh = tap / 3 - 1, dw = tap % 3 - 1;
        const int shift = (dh * W + dw) * CIN;
#pragma unroll
        for (int kc = 0; kc < 4; ++kc) {
            __syncthreads();
#pragma unroll
            for (int i = 0; i < 4; ++i) {
                int ih = ohs[i] + dh, iw = ows[i] + dw;
                bool valid = ((unsigned)ih < (unsigned)H) & ((unsigned)iw < (unsigned)W);
                f32x4 v = {0.f, 0.f, 0.f, 0.f};
                if (valid) v = *(const f32x4*)(x + bases[i] + shift + kc * 32 + c4);
                u16x4 s = { f2bf(v.x), f2bf(v.y), f2bf(v.z), f2bf(v.w) };
                *(u16x4*)&As[rseg + i * 32][c4] = s;
            }
            const unsigned short* bp = bw + tap * 32768 + kc * 8192 + bn * 4096;
#pragma unroll
            for (int j = 0; j < 2; ++j) {
                int idx = tid + j * 256;
                *(u16x8*)&Bs[idx >> 2][(idx & 3) * 8] = *(const u16x8*)(bp + (idx >> 2) * 32 + (idx & 3) * 8);
            }
            __syncthreads();
            short8 af[4], bfr[4];
#pragma unroll
            for (int m = 0; m < 4; ++m)
                af[m] = *(const short8*)&As[arow + m * 16][koff];
#pragma unroll
            for (int n = 0; n < 4; ++n)
                bfr[n] = *(const short8*)&Bs[brow + n * 16][koff];
#pragma unroll
            for (int m = 0; m < 4; ++m)
#pragma unroll
                for (int n = 0; n < 4; ++n)
                    acc[m][n] = __builtin_amdgcn_mfma_f32_16x16x32_bf16(af[m], bfr[n], acc[m][n], 0, 0, 0);
        }
    }
    const long row0 = (long)bm * 128 + wr * 64 + ((lane >> 4) * 4);
    const int col = bn * 128 + wc * 64 + (lane & 15);
#pragma unroll
    for (int m = 0; m < 4; ++m)
#pragma unroll
        for (int n = 0; n < 4; ++n)
#pragma unroll
            for (int j = 0; j < 4; ++j)
                out[(row0 + m * 16 + j) * COUT + col + n * 16] = acc[m][n][j];
}

extern "C" void kernel_launch(void* const* d_in, const int* in_sizes, int n_in,
                              void* d_out, int out_size, void* d_ws, size_t ws_size,
                              hipStream_t stream) {
    const float* x  = (const float*)d_in[0];
    const float* kw = (const float*)d_in[1];
    float* out = (float*)d_out;
    unsigned short* bw = (unsigned short*)d_ws;           // 589,824 bytes
    const size_t BW_BYTES = 9 * 4 * 256 * 32 * 2;
    const size_t PAD_BYTES = (size_t)PADELEMS * 2;        // ~106.5 MB

    binw_kernel<<<(9 * 256 * 128) / 256, 256, 0, stream>>>(kw, bw);

    if (ws_size >= BW_BYTES + PAD_BYTES) {
        unsigned short* xp = (unsigned short*)((char*)d_ws + BW_BYTES);
        pad_kernel<<<(int)((PADELEMS / 8 + 255) / 256), 256, 0, stream>>>(x, xp);
        dim3 grid(MTOT / 128, COUT / 128);
        conv2_kernel<<<grid, 256, 0, stream>>>(xp, bw, out);
    } else {
        dim3 grid(MTOT / 128, COUT / 128);
        conv_fallback_kernel<<<grid, 256, 0, stream>>>(x, bw, out);
    }
}